// Round 17
// baseline (250.774 us; speedup 1.0000x reference)
//
#include <hip/hip_runtime.h>
#include <hip/hip_bf16.h>

#define DIM   1024
#define NHEAD 16
#define HDIM  64
#define BATCH 4
#define SEQ   1024
#define MTOT  (BATCH*SEQ)   // 4096
#define DFF   (4*DIM)       // 4096
#define LDQ   3072          // fused QKV row stride

typedef _Float16 f16x8 __attribute__((ext_vector_type(8)));
typedef _Float16 f16x4 __attribute__((ext_vector_type(4)));
typedef float    f32x4 __attribute__((ext_vector_type(4)));

// gelu(x) = 0.5x(1+tanh(z)) == x * sigmoid(2z), z = c(x + 0.044715 x^3).
__device__ __forceinline__ float geluf(float x) {
    float z2 = 1.5957691216057308f * (x + 0.044715f * x * x * x);  // 2*c*(...)
    return x * __builtin_amdgcn_rcpf(1.0f + __expf(-z2));
}

// Swizzled LDS byte offset for tiles with 64-f16 (128 B) rows, 8 slots of 16 B.
__device__ __forceinline__ int swz_off(int row, int slot) {
    return row * 128 + ((slot ^ (row & 7)) << 4);
}
__device__ __forceinline__ f16x8 ldsfrag(const _Float16* s, int row, int slot) {
    return *(const f16x8*)((const char*)s + swz_off(row, slot));
}

// Async global->LDS staging: linear LDS dest (wave-uniform base + lane*16),
// inverse-swizzled GLOBAL source so stored layout == swizzled layout (m173).
template <int NCHUNK>
__device__ __forceinline__ void stage_async(const _Float16* __restrict__ g, int ld,
                                            _Float16* s, int w, int lane) {
    int r_in = lane >> 3;               // 0..7 row within chunk
    int sslot = lane & 7;               // stored 16B slot
    int lslot = sslot ^ r_in;           // logical slot (row&7 == r_in)
#pragma unroll
    for (int q = 0; q < NCHUNK; ++q) {
        int chunk = w * NCHUNK + q;
        int row = chunk * 8 + r_in;
        const _Float16* gp = g + (size_t)row * ld + lslot * 8;
        _Float16* sp = s + chunk * 512;  // wave-uniform
        __builtin_amdgcn_global_load_lds(
            (const __attribute__((address_space(1))) void*)gp,
            (__attribute__((address_space(3))) void*)sp, 16, 0, 0);
    }
}

// ---------------- transpose + fp32->f16 convert:  src[K][N] -> dst[N][K] ----
__global__ __launch_bounds__(256) void k_tcvt(const float* __restrict__ src,
                                              _Float16* __restrict__ dst,
                                              int K, int N) {
    __shared__ float tile[32][33];
    int n0 = blockIdx.x * 32, k0 = blockIdx.y * 32;
    int tx = threadIdx.x, ty = threadIdx.y;
#pragma unroll
    for (int i = 0; i < 32; i += 8)
        tile[ty + i][tx] = src[(size_t)(k0 + ty + i) * N + (n0 + tx)];
    __syncthreads();
#pragma unroll
    for (int i = 0; i < 32; i += 8)
        dst[(size_t)(n0 + ty + i) * K + (k0 + tx)] = (_Float16)tile[tx][ty + i];
}

// four 1024x1024 transposes in one launch (z picks the source; dst slices are
// contiguous: z=0..2 -> WTqkv, z=3 -> WTo which sits right after in ws)
__global__ __launch_bounds__(256) void k_tcvt4(const float* __restrict__ s0,
                                               const float* __restrict__ s1,
                                               const float* __restrict__ s2,
                                               const float* __restrict__ s3,
                                               _Float16* __restrict__ dst) {
    __shared__ float tile[32][33];
    const float* src = blockIdx.z == 0 ? s0 : (blockIdx.z == 1 ? s1 :
                       (blockIdx.z == 2 ? s2 : s3));
    _Float16* d = dst + (size_t)blockIdx.z * (1024 * 1024);
    int n0 = blockIdx.x * 32, k0 = blockIdx.y * 32;
    int tx = threadIdx.x, ty = threadIdx.y;
#pragma unroll
    for (int i = 0; i < 32; i += 8)
        tile[ty + i][tx] = src[(size_t)(k0 + ty + i) * 1024 + (n0 + tx)];
    __syncthreads();
#pragma unroll
    for (int i = 0; i < 32; i += 8)
        d[(size_t)(n0 + ty + i) * 1024 + (k0 + tx)] = (_Float16)tile[tx][ty + i];
}

// ---------------- LayerNorm (fp32 in -> f16 out), one block per row ---------
__global__ __launch_bounds__(256) void k_ln(const float* __restrict__ x,
                                            const float* __restrict__ sc,
                                            const float* __restrict__ sh,
                                            _Float16* __restrict__ out) {
    int row = blockIdx.x;
    int t = threadIdx.x;
    float4 v = ((const float4*)(x + (size_t)row * DIM))[t];
    float sum = v.x + v.y + v.z + v.w;
    float sq  = v.x * v.x + v.y * v.y + v.z * v.z + v.w * v.w;
#pragma unroll
    for (int m = 1; m < 64; m <<= 1) {
        sum += __shfl_xor(sum, m);
        sq  += __shfl_xor(sq, m);
    }
    __shared__ float rs[4], rq[4];
    int w = t >> 6;
    if ((t & 63) == 0) { rs[w] = sum; rq[w] = sq; }
    __syncthreads();
    sum = rs[0] + rs[1] + rs[2] + rs[3];
    sq  = rq[0] + rq[1] + rq[2] + rq[3];
    float mean = sum * (1.0f / DIM);
    float var  = sq * (1.0f / DIM) - mean * mean;
    float rstd = rsqrtf(var + 1e-5f);
    float4 s4 = ((const float4*)sc)[t];
    float4 b4 = ((const float4*)sh)[t];
    f16x4 o;
    o[0] = (_Float16)(s4.x * ((v.x - mean) * rstd) + b4.x);
    o[1] = (_Float16)(s4.y * ((v.y - mean) * rstd) + b4.y);
    o[2] = (_Float16)(s4.z * ((v.z - mean) * rstd) + b4.z);
    o[3] = (_Float16)(s4.w * ((v.w - mean) * rstd) + b4.w);
    ((f16x4*)(out + (size_t)row * DIM))[t] = o;
}

// ---------------- GEMM 128x128, BK=64, counted-vmcnt 2-phase, XCD-chunked ---
// (for N>=3072 outputs: QKV, FF1 — grids 768/1024 blocks, 2 blocks/CU)
// EPI: 0 = plain f16; 1 = +bias,gelu f16
template <int EPI>
__global__ __launch_bounds__(256) void k_gemm(const _Float16* __restrict__ A,
                                              const _Float16* __restrict__ BT,
                                              int N, int K, int gx,
                                              _Float16* __restrict__ Ch,
                                              const float* __restrict__ bias) {
    __shared__ _Float16 As[2][128 * 64];
    __shared__ _Float16 Bs[2][128 * 64];
    int t = threadIdx.x;
    int bid = blockIdx.x;
    int lin = (bid & 7) * ((int)gridDim.x >> 3) + (bid >> 3);
    int m0 = (lin / gx) * 128, n0 = (lin % gx) * 128;
    int lane = t & 63, w = t >> 6;
    int wm = (w >> 1) * 64, wn = (w & 1) * 64;
    int lr = lane & 15, lg = lane >> 4;
    f32x4 acc[4][4];
#pragma unroll
    for (int i = 0; i < 4; ++i)
#pragma unroll
        for (int j = 0; j < 4; ++j) acc[i][j] = (f32x4){0.f, 0.f, 0.f, 0.f};

    const _Float16* Ag = A  + (size_t)m0 * K;
    const _Float16* Bg = BT + (size_t)n0 * K;
    int nt = K / 64;
    stage_async<4>(Ag, K, As[0], w, lane);
    stage_async<4>(Bg, K, Bs[0], w, lane);
    for (int tt = 0; tt < nt; ++tt) {
        int cur = tt & 1, nxt = cur ^ 1;
        if (tt + 1 < nt) {
            stage_async<4>(Ag + (tt + 1) * 64, K, As[nxt], w, lane);
            stage_async<4>(Bg + (tt + 1) * 64, K, Bs[nxt], w, lane);
            asm volatile("s_waitcnt vmcnt(8)" ::: "memory");
        } else {
            asm volatile("s_waitcnt vmcnt(0)" ::: "memory");
        }
        __builtin_amdgcn_sched_barrier(0);
        __builtin_amdgcn_s_barrier();
        __builtin_amdgcn_sched_barrier(0);
#pragma unroll
        for (int kk = 0; kk < 2; ++kk) {
            f16x8 a[4], b[4];
#pragma unroll
            for (int i = 0; i < 4; ++i) a[i] = ldsfrag(As[cur], wm + i * 16 + lr, kk * 4 + lg);
#pragma unroll
            for (int j = 0; j < 4; ++j) b[j] = ldsfrag(Bs[cur], wn + j * 16 + lr, kk * 4 + lg);
            __builtin_amdgcn_s_setprio(1);
#pragma unroll
            for (int i = 0; i < 4; ++i)
#pragma unroll
                for (int j = 0; j < 4; ++j)
                    acc[i][j] = __builtin_amdgcn_mfma_f32_16x16x32_f16(a[i], b[j], acc[i][j], 0, 0, 0);
            __builtin_amdgcn_s_setprio(0);
        }
        __builtin_amdgcn_s_barrier();   // buf[cur] reads done before overwrite
    }
#pragma unroll
    for (int i = 0; i < 4; ++i) {
#pragma unroll
        for (int j = 0; j < 4; ++j) {
            int row = m0 + wm + i * 16 + lg * 4;
            int col = n0 + wn + j * 16 + lr;
#pragma unroll
            for (int r = 0; r < 4; ++r) {
                float v = acc[i][j][r];
                size_t idx = (size_t)(row + r) * N + col;
                if constexpr (EPI == 0) Ch[idx] = (_Float16)v;
                else                    Ch[idx] = (_Float16)geluf(v + bias[col]);
            }
        }
    }
}

// ---------------- GEMM 128x64 (N=1024: Wo, FF2) -----------------------------
// A direct-to-register (each wave's 32 A-rows are EXCLUSIVE -> LDS round-trip
// for A is pure waste), B-only 3-buffer LDS counted-vmcnt pipeline. Per step
// per wave issue order: A-regs(4 dwordx4) then B-stage(2 lds) -> at top of
// step u outstanding = A(u)4+B(u)2+A(u+1)4+B(u+1)2 = 12; vmcnt(6) waits
// exactly A(u)+B(u). A(u+2) overwrites the buffer compute(u) just read
// (same-wave program order, safe). Barrier at top guards B buffer reuse.
__device__ __forceinline__ void load_a_regs(const _Float16* __restrict__ Ag, int K,
                                            int koff, int wm, int lr, int lg,
                                            f16x8 (&ar)[2][2]) {
#pragma unroll
    for (int i = 0; i < 2; ++i)
#pragma unroll
        for (int kk = 0; kk < 2; ++kk)
            ar[i][kk] = *(const f16x8*)(Ag + (size_t)(wm + i * 16 + lr) * K + koff + kk * 32 + lg * 8);
}

__device__ __forceinline__ void g64_step(int u, int nt,
                                         const _Float16* __restrict__ Ag,
                                         const _Float16* __restrict__ Bg, int K,
                                         _Float16 (*Bs)[64 * 64],
                                         f16x8 (&AR)[2][2], f32x4 (&acc)[2][4],
                                         int w, int lane, int wm, int lr, int lg) {
    if (u + 1 < nt) asm volatile("s_waitcnt vmcnt(6)" ::: "memory");
    else            asm volatile("s_waitcnt vmcnt(0)" ::: "memory");
    __builtin_amdgcn_sched_barrier(0);
    __builtin_amdgcn_s_barrier();
    __builtin_amdgcn_sched_barrier(0);
    const _Float16* Bc = Bs[u % 3];
#pragma unroll
    for (int kk = 0; kk < 2; ++kk) {
        f16x8 b[4];
#pragma unroll
        for (int j = 0; j < 4; ++j) b[j] = ldsfrag(Bc, j * 16 + lr, kk * 4 + lg);
        __builtin_amdgcn_s_setprio(1);
#pragma unroll
        for (int i = 0; i < 2; ++i)
#pragma unroll
            for (int j = 0; j < 4; ++j)
                acc[i][j] = __builtin_amdgcn_mfma_f32_16x16x32_f16(AR[i][kk], b[j], acc[i][j], 0, 0, 0);
        __builtin_amdgcn_s_setprio(0);
    }
    if (u + 2 < nt) {
        load_a_regs(Ag, K, (u + 2) * 64, wm, lr, lg, AR);
        stage_async<2>(Bg + (u + 2) * 64, K, Bs[(u + 2) % 3], w, lane);
    }
}

__global__ __launch_bounds__(256) void k_gemm64(const _Float16* __restrict__ A,
                                                const _Float16* __restrict__ BT,
                                                int N, int K,
                                                float* __restrict__ Cf,
                                                const float* __restrict__ bias,
                                                const float* __restrict__ resid) {
    __shared__ _Float16 Bs[3][64 * 64];
    int t = threadIdx.x;
    int bid = blockIdx.x;
    int lin = (bid & 7) * ((int)gridDim.x >> 3) + (bid >> 3);
    int gx = N / 64;
    int m0 = (lin / gx) * 128, n0 = (lin % gx) * 64;
    int lane = t & 63, w = t >> 6;
    int wm = w * 32;
    int lr = lane & 15, lg = lane >> 4;
    f32x4 acc[2][4];
#pragma unroll
    for (int i = 0; i < 2; ++i)
#pragma unroll
        for (int j = 0; j < 4; ++j) acc[i][j] = (f32x4){0.f, 0.f, 0.f, 0.f};

    const _Float16* Ag = A  + (size_t)m0 * K;
    const _Float16* Bg = BT + (size_t)n0 * K;
    int nt = K / 64;   // even (16 or 64)
    f16x8 aA[2][2], aB[2][2];
    // prologue: tiles 0 and 1 in flight (A-regs + B-stage each)
    load_a_regs(Ag, K, 0, wm, lr, lg, aA);
    stage_async<2>(Bg, K, Bs[0], w, lane);
    load_a_regs(Ag, K, 64, wm, lr, lg, aB);
    stage_async<2>(Bg + 64, K, Bs[1], w, lane);
    for (int tt = 0; tt < nt; tt += 2) {
        g64_step(tt,     nt, Ag, Bg, K, Bs, aA, acc, w, lane, wm, lr, lg);
        g64_step(tt + 1, nt, Ag, Bg, K, Bs, aB, acc, w, lane, wm, lr, lg);
    }
#pragma unroll
    for (int i = 0; i < 2; ++i) {
#pragma unroll
        for (int j = 0; j < 4; ++j) {
            int row = m0 + wm + i * 16 + lg * 4;
            int col = n0 + j * 16 + lr;
#pragma unroll
            for (int r = 0; r < 4; ++r) {
                size_t idx = (size_t)(row + r) * N + col;
                Cf[idx] = acc[i][j][r] + bias[col] + resid[idx];
            }
        }
    }
}

// ---------------- Flash attention: swapped-operand QK^T/PV ------------------
// 1 wave per (b, h, 32-row q-tile); LPT heavy-first grid; V direct-from-global.
// QK^T computed as mfma(K, Q): C/D col (=lane&15) indexes the Q-ROW, so each
// lane holds a full 16-wide k-slice of ONE q-row -> softmax row-reduce is an
// in-lane tree + 2 shfl_xor. PV computed as mfma(V, P): accumulator col also
// = q-row -> rescale is lane-local. P staged via LDS (8B vector writes).
__global__ __launch_bounds__(64) void k_attn(const _Float16* __restrict__ QKV,
                                             _Float16* __restrict__ Og) {
    __shared__ _Float16 Ps[32 * 64];  // P[q][k], swizzled (4 KB)
    int lane = threadIdx.x;
    int id = blockIdx.x;
    int bh = id & 63;
    int qt = (SEQ / 32 - 1) - (id >> 6);  // heavy blocks dispatch first
    int h = bh & 15, b = bh >> 4;
    int q0 = qt * 32;
    int lr = lane & 15, lg = lane >> 4;
    size_t base = (size_t)b * SEQ;
    int cq = h * HDIM, ck = 1024 + h * HDIM, cv = 2048 + h * HDIM;

    // Q fragments (B-operand: col=lane&15 -> q-row, k=(lane>>4)*8+e), scaled
    f16x8 aq[2][2];
#pragma unroll
    for (int i = 0; i < 2; ++i)
#pragma unroll
        for (int kk = 0; kk < 2; ++kk) {
            f16x8 v = *(const f16x8*)(QKV + (base + q0 + i * 16 + lr) * LDQ + cq + kk * 32 + lg * 8);
#pragma unroll
            for (int e = 0; e < 8; ++e) v[e] = v[e] * (_Float16)0.125f;
            aq[i][kk] = v;
        }

    // cacc[i][jd]: D col=lane&15 = q-row (i*16+lr), row = d = jd*16+lg*4+r
    f32x4 cacc[2][4];
#pragma unroll
    for (int i = 0; i < 2; ++i)
#pragma unroll
        for (int j = 0; j < 4; ++j) cacc[i][j] = (f32x4){0.f, 0.f, 0.f, 0.f};
    float mrun[2], lrun[2];
#pragma unroll
    for (int i = 0; i < 2; ++i) { mrun[i] = -1e30f; lrun[i] = 0.f; }

    int ntiles = q0 / 64 + 1;   // 64-wide K/V tiles needed for causal rows
    for (int kt = 0; kt < ntiles; ++kt) {
        int k0 = kt * 64;
        // scores^T = K Q^T: sacc[i][j] col = q-row (i*16+lr), row = k (j*16+lg*4+r)
        f32x4 sacc[2][4];
#pragma unroll
        for (int i = 0; i < 2; ++i)
#pragma unroll
            for (int j = 0; j < 4; ++j) sacc[i][j] = (f32x4){0.f, 0.f, 0.f, 0.f};
#pragma unroll
        for (int kk = 0; kk < 2; ++kk) {
            f16x8 bk[4];
#pragma unroll
            for (int j = 0; j < 4; ++j)
                bk[j] = *(const f16x8*)(QKV + (base + k0 + j * 16 + lr) * LDQ + ck + kk * 32 + lg * 8);
            __builtin_amdgcn_s_setprio(1);
#pragma unroll
            for (int i = 0; i < 2; ++i)
#pragma unroll
                for (int j = 0; j < 4; ++j)
                    sacc[i][j] = __builtin_amdgcn_mfma_f32_16x16x32_f16(bk[j], aq[i][kk], sacc[i][j], 0, 0, 0);
            __builtin_amdgcn_s_setprio(0);
        }
        // causal mask (last tile only): qq = q0+i*16+lr, kc = k0+j*16+lg*4+r
        if (kt == ntiles - 1) {
#pragma unroll
            for (int i = 0; i < 2; ++i) {
                int qq = q0 + i * 16 + lr;
#pragma unroll
                for (int j = 0; j < 4; ++j)
#pragma unroll
                    for (int r = 0; r < 4; ++r) {
                        int kc = k0 + j * 16 + lg * 4 + r;
                        if (kc > qq) sacc[i][j][r] = -1e30f;
                    }
            }
        }
        // online softmax: per i, all 16 values in-lane belong to q-row i*16+lr
#pragma unroll
        for (int i = 0; i < 2; ++i) {
            float tm = -1e30f;
#pragma unroll
            for (int j = 0; j < 4; ++j)
#pragma unroll
                for (int r = 0; r < 4; ++r) tm = fmaxf(tm, sacc[i][j][r]);
            tm = fmaxf(tm, __shfl_xor(tm, 16));
            tm = fmaxf(tm, __shfl_xor(tm, 32));
            float m2 = fmaxf(mrun[i], tm);
            float al = __expf(mrun[i] - m2);
            mrun[i] = m2;
#pragma unroll
            for (int jd = 0; jd < 4; ++jd)
#pragma unroll
                for (int r = 0; r < 4; ++r) cacc[i][jd][r] *= al;
            float ps = 0.f;
#pragma unroll
            for (int j = 0; j < 4; ++j)
#pragma unroll
                for (int r = 0; r < 4; ++r) {
                    float p = __expf(sacc[i][j][r] - m2);
                    sacc[i][j][r] = p;
                    ps += p;
                }
            ps += __shfl_xor(ps, 16);
            ps += __shfl_xor(ps, 32);
            lrun[i] = lrun[i] * al + ps;
        }
        // P -> LDS: row q=i*16+lr, kc=j*16+lg*4+{0..3} consecutive -> 8B writes
#pragma unroll
        for (int i = 0; i < 2; ++i) {
            int q = i * 16 + lr;
#pragma unroll
            for (int j = 0; j < 4; ++j) {
                int kc0 = j * 16 + lg * 4;
                int ks = kc0 >> 3;
                f16x4 pv4;
#pragma unroll
                for (int r = 0; r < 4; ++r) pv4[r] = (_Float16)sacc[i][j][r];
                *(f16x4*)((char*)Ps + q * 128 + ((ks ^ (q & 7)) << 4) + (kc0 & 7) * 2) = pv4;
            }
        }
        // PV: cacc[i][jd] += mfma(V-frag as A, P as B). V direct from global:
        // bv[jd][e] = V[k0+kk*32+lg*8+e][cv + jd*16 + lr]  (A row = d-in-block)
        {
            const _Float16* vb = QKV + (base + k0) * LDQ + cv;
#pragma unroll
            for (int kk = 0; kk < 2; ++kk) {
                f16x8 pa[2], bv[4];
#pragma unroll
                for (int i = 0; i < 2; ++i) pa[i] = ldsfrag(Ps, i * 16 + lr, kk * 4 + lg);
                const _Float16* vk = vb + (size_t)(kk * 32 + lg * 8) * LDQ + lr;
#pragma unroll
                for (int jd = 0; jd < 4; ++jd)
#pragma unroll
                    for (int e = 0; e < 8; ++e)
                        bv[jd][e] = vk[(size_t)e * LDQ + jd * 16];
                __builtin_amdgcn_s_setprio(1);
#pragma unroll
                for (int i = 0; i < 2; ++i)
#pragma unroll
                    for (int jd = 0; jd < 4; ++jd)
                        cacc[i][jd] = __builtin_amdgcn_mfma_f32_16x16x32_f16(bv[jd], pa[i], cacc[i][jd], 0, 0, 0);
                __builtin_amdgcn_s_setprio(0);
            }
        }
    }
    // normalize + write ctx: q = q0+i*16+lr, d = jd*16+lg*4+{0..3} -> 8B stores
#pragma unroll
    for (int i = 0; i < 2; ++i) {
        float rl = 1.0f / lrun[i];
        int qq = q0 + i * 16 + lr;
#pragma unroll
        for (int jd = 0; jd < 4; ++jd) {
            f16x4 o4;
#pragma unroll
            for (int r = 0; r < 4; ++r) o4[r] = (_Float16)(cacc[i][jd][r] * rl);
            *(f16x4*)(Og + (base + qq) * DIM + h * HDIM + jd * 16 + lg * 4) = o4;
        }
    }
}

// ---------------------------------------------------------------------------
extern "C" void kernel_launch(void* const* d_in, const int* in_sizes, int n_in,
                              void* d_out, int out_size, void* d_ws, size_t ws_size,
                              hipStream_t stream) {
    const float* x    = (const float*)d_in[0];
    const float* WQ   = (const float*)d_in[1];
    const float* WK   = (const float*)d_in[2];
    const float* WV   = (const float*)d_in[3];
    const float* Wo   = (const float*)d_in[4];
    const float* bo   = (const float*)d_in[5];
    const float* W1   = (const float*)d_in[6];
    const float* b1   = (const float*)d_in[7];
    const float* W2   = (const float*)d_in[8];
    const float* b2   = (const float*)d_in[9];
    const float* ln1s = (const float*)d_in[10];
    const float* ln1b = (const float*)d_in[11];
    const float* ln2s = (const float*)d_in[12];
    const float* ln2b = (const float*)d_in[13];
    float* out = (float*)d_out;
    char* ws = (char*)d_ws;
    const size_t MB = 1024 * 1024;
    _Float16* WTqkv = (_Float16*)(ws + 0 * MB);   // [3072][1024] = 6MB
    _Float16* WTo   = (_Float16*)(ws + 6 * MB);   // contiguous after WTqkv
    _Float16* WT1   = (_Float16*)(ws + 8 * MB);   // [4096][1024]
    _Float16* WT2   = (_Float16*)(ws + 16 * MB);  // [1024][4096]
    _Float16* h1    = (_Float16*)(ws + 24 * MB);
    _Float16* qkvb  = (_Float16*)(ws + 32 * MB);  // [4096][3072] = 24MB
    _Float16* ctx   = (_Float16*)(ws + 56 * MB);
    _Float16* h2    = (_Float16*)(ws + 64 * MB);
    _Float16* ff1   = (_Float16*)(ws + 72 * MB);  // [4096][4096] = 32MB
    float*    x2    = (float*)   (ws + 104 * MB); // fp32 residual = 16MB

    dim3 tb(32, 8);
    k_tcvt4<<<dim3(32, 32, 4), tb, 0, stream>>>(WQ, WK, WV, Wo, WTqkv);
    k_tcvt<<<dim3(128, 32), tb, 0, stream>>>(W1, WT1, 1024, 4096);
    k_tcvt<<<dim3(32, 128), tb, 0, stream>>>(W2, WT2, 4096, 1024);

    k_ln<<<MTOT, 256, 0, stream>>>(x, ln1s, ln1b, h1);

    // fused QKV: [4096,1024] x [1024,3072] -> [4096,3072]  (24x32 tiles)
    k_gemm<0><<<dim3(768), 256, 0, stream>>>(h1, WTqkv, LDQ, DIM, 24, qkvb, nullptr);

    k_attn<<<dim3(2048), 64, 0, stream>>>(qkvb, ctx);

    // x2 = x + ctx @ Wo + bo   (512 blocks of 128x64, A-reg + B-LDS pipeline)
    k_gemm64<<<dim3(512), 256, 0, stream>>>(ctx, WTo, DIM, DIM, x2, bo, x);

    k_ln<<<MTOT, 256, 0, stream>>>(x2, ln2s, ln2b, h2);

    // ff1 = gelu(h2 @ W1 + b1)  (32x32 tiles)
    k_gemm<1><<<dim3(1024), 256, 0, stream>>>(h2, WT1, DFF, DIM, 32, ff1, b1);

    // out = x2 + ff1 @ W2 + b2  (512 blocks of 128x64, A-reg + B-LDS pipeline)
    k_gemm64<<<dim3(512), 256, 0, stream>>>(ff1, WT2, DIM, DFF, out, b2, x2);
}

// Round 18
// 218.289 us; speedup vs baseline: 1.1488x; 1.1488x over previous
//
#include <hip/hip_runtime.h>
#include <hip/hip_bf16.h>

#define DIM   1024
#define NHEAD 16
#define HDIM  64
#define BATCH 4
#define SEQ   1024
#define MTOT  (BATCH*SEQ)   // 4096
#define DFF   (4*DIM)       // 4096
#define LDQ   3072          // fused QKV row stride

typedef _Float16 f16x8 __attribute__((ext_vector_type(8)));
typedef _Float16 f16x4 __attribute__((ext_vector_type(4)));
typedef float    f32x4 __attribute__((ext_vector_type(4)));

// gelu(x) = 0.5x(1+tanh(z)) == x * sigmoid(2z), z = c(x + 0.044715 x^3).
__device__ __forceinline__ float geluf(float x) {
    float z2 = 1.5957691216057308f * (x + 0.044715f * x * x * x);  // 2*c*(...)
    return x * __builtin_amdgcn_rcpf(1.0f + __expf(-z2));
}

// Swizzled LDS byte offset for tiles with 64-f16 (128 B) rows, 8 slots of 16 B.
__device__ __forceinline__ int swz_off(int row, int slot) {
    return row * 128 + ((slot ^ (row & 7)) << 4);
}
__device__ __forceinline__ f16x8 ldsfrag(const _Float16* s, int row, int slot) {
    return *(const f16x8*)((const char*)s + swz_off(row, slot));
}

// Async global->LDS staging: linear LDS dest (wave-uniform base + lane*16),
// inverse-swizzled GLOBAL source so stored layout == swizzled layout (m173).
template <int NCHUNK>
__device__ __forceinline__ void stage_async(const _Float16* __restrict__ g, int ld,
                                            _Float16* s, int w, int lane) {
    int r_in = lane >> 3;               // 0..7 row within chunk
    int sslot = lane & 7;               // stored 16B slot
    int lslot = sslot ^ r_in;           // logical slot (row&7 == r_in)
#pragma unroll
    for (int q = 0; q < NCHUNK; ++q) {
        int chunk = w * NCHUNK + q;
        int row = chunk * 8 + r_in;
        const _Float16* gp = g + (size_t)row * ld + lslot * 8;
        _Float16* sp = s + chunk * 512;  // wave-uniform
        __builtin_amdgcn_global_load_lds(
            (const __attribute__((address_space(1))) void*)gp,
            (__attribute__((address_space(3))) void*)sp, 16, 0, 0);
    }
}

// ---------------- transpose + fp32->f16 convert:  src[K][N] -> dst[N][K] ----
__global__ __launch_bounds__(256) void k_tcvt(const float* __restrict__ src,
                                              _Float16* __restrict__ dst,
                                              int K, int N) {
    __shared__ float tile[32][33];
    int n0 = blockIdx.x * 32, k0 = blockIdx.y * 32;
    int tx = threadIdx.x, ty = threadIdx.y;
#pragma unroll
    for (int i = 0; i < 32; i += 8)
        tile[ty + i][tx] = src[(size_t)(k0 + ty + i) * N + (n0 + tx)];
    __syncthreads();
#pragma unroll
    for (int i = 0; i < 32; i += 8)
        dst[(size_t)(n0 + ty + i) * K + (k0 + tx)] = (_Float16)tile[tx][ty + i];
}

// four 1024x1024 transposes in one launch (z picks the source; dst slices are
// contiguous: z=0..2 -> WTqkv, z=3 -> WTo which sits right after in ws)
__global__ __launch_bounds__(256) void k_tcvt4(const float* __restrict__ s0,
                                               const float* __restrict__ s1,
                                               const float* __restrict__ s2,
                                               const float* __restrict__ s3,
                                               _Float16* __restrict__ dst) {
    __shared__ float tile[32][33];
    const float* src = blockIdx.z == 0 ? s0 : (blockIdx.z == 1 ? s1 :
                       (blockIdx.z == 2 ? s2 : s3));
    _Float16* d = dst + (size_t)blockIdx.z * (1024 * 1024);
    int n0 = blockIdx.x * 32, k0 = blockIdx.y * 32;
    int tx = threadIdx.x, ty = threadIdx.y;
#pragma unroll
    for (int i = 0; i < 32; i += 8)
        tile[ty + i][tx] = src[(size_t)(k0 + ty + i) * 1024 + (n0 + tx)];
    __syncthreads();
#pragma unroll
    for (int i = 0; i < 32; i += 8)
        d[(size_t)(n0 + ty + i) * 1024 + (k0 + tx)] = (_Float16)tile[tx][ty + i];
}

// ---------------- LayerNorm (fp32 in -> f16 out), one block per row ---------
__global__ __launch_bounds__(256) void k_ln(const float* __restrict__ x,
                                            const float* __restrict__ sc,
                                            const float* __restrict__ sh,
                                            _Float16* __restrict__ out) {
    int row = blockIdx.x;
    int t = threadIdx.x;
    float4 v = ((const float4*)(x + (size_t)row * DIM))[t];
    float sum = v.x + v.y + v.z + v.w;
    float sq  = v.x * v.x + v.y * v.y + v.z * v.z + v.w * v.w;
#pragma unroll
    for (int m = 1; m < 64; m <<= 1) {
        sum += __shfl_xor(sum, m);
        sq  += __shfl_xor(sq, m);
    }
    __shared__ float rs[4], rq[4];
    int w = t >> 6;
    if ((t & 63) == 0) { rs[w] = sum; rq[w] = sq; }
    __syncthreads();
    sum = rs[0] + rs[1] + rs[2] + rs[3];
    sq  = rq[0] + rq[1] + rq[2] + rq[3];
    float mean = sum * (1.0f / DIM);
    float var  = sq * (1.0f / DIM) - mean * mean;
    float rstd = rsqrtf(var + 1e-5f);
    float4 s4 = ((const float4*)sc)[t];
    float4 b4 = ((const float4*)sh)[t];
    f16x4 o;
    o[0] = (_Float16)(s4.x * ((v.x - mean) * rstd) + b4.x);
    o[1] = (_Float16)(s4.y * ((v.y - mean) * rstd) + b4.y);
    o[2] = (_Float16)(s4.z * ((v.z - mean) * rstd) + b4.z);
    o[3] = (_Float16)(s4.w * ((v.w - mean) * rstd) + b4.w);
    ((f16x4*)(out + (size_t)row * DIM))[t] = o;
}

// ---------------- GEMM 128x128, BK=64, counted-vmcnt 2-phase, XCD-chunked ---
// (for N>=3072 outputs: QKV, FF1 — grids 768/1024 blocks, 2 blocks/CU)
// EPI: 0 = plain f16; 1 = +bias,gelu f16
template <int EPI>
__global__ __launch_bounds__(256) void k_gemm(const _Float16* __restrict__ A,
                                              const _Float16* __restrict__ BT,
                                              int N, int K, int gx,
                                              _Float16* __restrict__ Ch,
                                              const float* __restrict__ bias) {
    __shared__ _Float16 As[2][128 * 64];
    __shared__ _Float16 Bs[2][128 * 64];
    int t = threadIdx.x;
    int bid = blockIdx.x;
    int lin = (bid & 7) * ((int)gridDim.x >> 3) + (bid >> 3);
    int m0 = (lin / gx) * 128, n0 = (lin % gx) * 128;
    int lane = t & 63, w = t >> 6;
    int wm = (w >> 1) * 64, wn = (w & 1) * 64;
    int lr = lane & 15, lg = lane >> 4;
    f32x4 acc[4][4];
#pragma unroll
    for (int i = 0; i < 4; ++i)
#pragma unroll
        for (int j = 0; j < 4; ++j) acc[i][j] = (f32x4){0.f, 0.f, 0.f, 0.f};

    const _Float16* Ag = A  + (size_t)m0 * K;
    const _Float16* Bg = BT + (size_t)n0 * K;
    int nt = K / 64;
    stage_async<4>(Ag, K, As[0], w, lane);
    stage_async<4>(Bg, K, Bs[0], w, lane);
    for (int tt = 0; tt < nt; ++tt) {
        int cur = tt & 1, nxt = cur ^ 1;
        if (tt + 1 < nt) {
            stage_async<4>(Ag + (tt + 1) * 64, K, As[nxt], w, lane);
            stage_async<4>(Bg + (tt + 1) * 64, K, Bs[nxt], w, lane);
            asm volatile("s_waitcnt vmcnt(8)" ::: "memory");
        } else {
            asm volatile("s_waitcnt vmcnt(0)" ::: "memory");
        }
        __builtin_amdgcn_sched_barrier(0);
        __builtin_amdgcn_s_barrier();
        __builtin_amdgcn_sched_barrier(0);
#pragma unroll
        for (int kk = 0; kk < 2; ++kk) {
            f16x8 a[4], b[4];
#pragma unroll
            for (int i = 0; i < 4; ++i) a[i] = ldsfrag(As[cur], wm + i * 16 + lr, kk * 4 + lg);
#pragma unroll
            for (int j = 0; j < 4; ++j) b[j] = ldsfrag(Bs[cur], wn + j * 16 + lr, kk * 4 + lg);
            __builtin_amdgcn_s_setprio(1);
#pragma unroll
            for (int i = 0; i < 4; ++i)
#pragma unroll
                for (int j = 0; j < 4; ++j)
                    acc[i][j] = __builtin_amdgcn_mfma_f32_16x16x32_f16(a[i], b[j], acc[i][j], 0, 0, 0);
            __builtin_amdgcn_s_setprio(0);
        }
        __builtin_amdgcn_s_barrier();   // buf[cur] reads done before overwrite
    }
#pragma unroll
    for (int i = 0; i < 4; ++i) {
#pragma unroll
        for (int j = 0; j < 4; ++j) {
            int row = m0 + wm + i * 16 + lg * 4;
            int col = n0 + wn + j * 16 + lr;
#pragma unroll
            for (int r = 0; r < 4; ++r) {
                float v = acc[i][j][r];
                size_t idx = (size_t)(row + r) * N + col;
                if constexpr (EPI == 0) Ch[idx] = (_Float16)v;
                else                    Ch[idx] = (_Float16)geluf(v + bias[col]);
            }
        }
    }
}

// ---------------- GEMM 128x64 (N=1024: Wo, FF2), 3-buffer counted-vmcnt -----
// R14-proven: stage(t+2) issued AFTER compute(t); vmcnt(6) waits exactly
// tile t's 6 loads (never drain mid-loop); barrier at top guards B reuse.
__global__ __launch_bounds__(256) void k_gemm64(const _Float16* __restrict__ A,
                                                const _Float16* __restrict__ BT,
                                                int N, int K,
                                                float* __restrict__ Cf,
                                                const float* __restrict__ bias,
                                                const float* __restrict__ resid) {
    __shared__ _Float16 As[3][128 * 64];
    __shared__ _Float16 Bs[3][64 * 64];
    int t = threadIdx.x;
    int bid = blockIdx.x;
    int lin = (bid & 7) * ((int)gridDim.x >> 3) + (bid >> 3);
    int gx = N / 64;
    int m0 = (lin / gx) * 128, n0 = (lin % gx) * 64;
    int lane = t & 63, w = t >> 6;
    int wm = w * 32;
    int lr = lane & 15, lg = lane >> 4;
    f32x4 acc[2][4];
#pragma unroll
    for (int i = 0; i < 2; ++i)
#pragma unroll
        for (int j = 0; j < 4; ++j) acc[i][j] = (f32x4){0.f, 0.f, 0.f, 0.f};

    const _Float16* Ag = A  + (size_t)m0 * K;
    const _Float16* Bg = BT + (size_t)n0 * K;
    int nt = K / 64;
    // prologue: tiles 0 and 1 in flight (12 outstanding per wave)
    stage_async<4>(Ag, K, As[0], w, lane);
    stage_async<2>(Bg, K, Bs[0], w, lane);
    stage_async<4>(Ag + 64, K, As[1], w, lane);
    stage_async<2>(Bg + 64, K, Bs[1], w, lane);
    for (int tt = 0; tt < nt; ++tt) {
        if (tt + 1 < nt) asm volatile("s_waitcnt vmcnt(6)" ::: "memory");
        else             asm volatile("s_waitcnt vmcnt(0)" ::: "memory");
        __builtin_amdgcn_sched_barrier(0);
        __builtin_amdgcn_s_barrier();
        __builtin_amdgcn_sched_barrier(0);
        const _Float16* Ac = As[tt % 3];
        const _Float16* Bc = Bs[tt % 3];
#pragma unroll
        for (int kk = 0; kk < 2; ++kk) {
            f16x8 a[2], b[4];
#pragma unroll
            for (int i = 0; i < 2; ++i) a[i] = ldsfrag(Ac, wm + i * 16 + lr, kk * 4 + lg);
#pragma unroll
            for (int j = 0; j < 4; ++j) b[j] = ldsfrag(Bc, j * 16 + lr, kk * 4 + lg);
            __builtin_amdgcn_s_setprio(1);
#pragma unroll
            for (int i = 0; i < 2; ++i)
#pragma unroll
                for (int j = 0; j < 4; ++j)
                    acc[i][j] = __builtin_amdgcn_mfma_f32_16x16x32_f16(a[i], b[j], acc[i][j], 0, 0, 0);
            __builtin_amdgcn_s_setprio(0);
        }
        if (tt + 2 < nt) {
            int nb = (tt + 2) % 3;
            stage_async<4>(Ag + (tt + 2) * 64, K, As[nb], w, lane);
            stage_async<2>(Bg + (tt + 2) * 64, K, Bs[nb], w, lane);
        }
    }
#pragma unroll
    for (int i = 0; i < 2; ++i) {
#pragma unroll
        for (int j = 0; j < 4; ++j) {
            int row = m0 + wm + i * 16 + lg * 4;
            int col = n0 + j * 16 + lr;
#pragma unroll
            for (int r = 0; r < 4; ++r) {
                size_t idx = (size_t)(row + r) * N + col;
                Cf[idx] = acc[i][j][r] + bias[col] + resid[idx];
            }
        }
    }
}

// ---------------- Flash attention: swapped-operand QK^T/PV ------------------
// 1 wave per (b, h, 32-row q-tile); LPT heavy-first grid; V direct-from-global.
// NEW (R18): K-fragment register double-buffer — tile t+1's K loads issued
// right after tile t's QK^T MFMAs, hiding K-load latency under softmax+PV.
// Named kA/kB buffers + unrolled-by-2 loop (rule #20: static indexing only).
__device__ __forceinline__ void load_k(const _Float16* __restrict__ QKV,
                                       size_t base, int k0, int ck,
                                       int lr, int lg, f16x8 (&kr)[2][4]) {
#pragma unroll
    for (int kk = 0; kk < 2; ++kk)
#pragma unroll
        for (int j = 0; j < 4; ++j)
            kr[kk][j] = *(const f16x8*)(QKV + (base + k0 + j * 16 + lr) * LDQ + ck + kk * 32 + lg * 8);
}

__device__ __forceinline__ void attn_tile_sw(const _Float16* __restrict__ QKV,
                                             const f16x8 (&bk)[2][4],
                                             f16x8 (&knext)[2][4], bool pf, int k0next,
                                             const f16x8 (&aq)[2][2],
                                             f32x4 (&cacc)[2][4],
                                             float (&mrun)[2], float (&lrun)[2],
                                             _Float16* Ps,
                                             size_t base, int ck, int cv,
                                             int k0, int q0, bool diag,
                                             int lr, int lg) {
    // scores^T = K Q^T: sacc[i][j] col = q-row (i*16+lr), row = k (j*16+lg*4+r)
    f32x4 sacc[2][4];
#pragma unroll
    for (int i = 0; i < 2; ++i)
#pragma unroll
        for (int j = 0; j < 4; ++j) sacc[i][j] = (f32x4){0.f, 0.f, 0.f, 0.f};
    __builtin_amdgcn_s_setprio(1);
#pragma unroll
    for (int kk = 0; kk < 2; ++kk)
#pragma unroll
        for (int i = 0; i < 2; ++i)
#pragma unroll
            for (int j = 0; j < 4; ++j)
                sacc[i][j] = __builtin_amdgcn_mfma_f32_16x16x32_f16(bk[kk][j], aq[i][kk], sacc[i][j], 0, 0, 0);
    __builtin_amdgcn_s_setprio(0);
    // prefetch next tile's K fragments (latency hides under softmax + PV)
    if (pf) load_k(QKV, base, k0next, ck, lr, lg, knext);
    // causal mask (diagonal tile only): qq = q0+i*16+lr, kc = k0+j*16+lg*4+r
    if (diag) {
#pragma unroll
        for (int i = 0; i < 2; ++i) {
            int qq = q0 + i * 16 + lr;
#pragma unroll
            for (int j = 0; j < 4; ++j)
#pragma unroll
                for (int r = 0; r < 4; ++r) {
                    int kc = k0 + j * 16 + lg * 4 + r;
                    if (kc > qq) sacc[i][j][r] = -1e30f;
                }
        }
    }
    // online softmax: per i, all 16 values in-lane belong to q-row i*16+lr
#pragma unroll
    for (int i = 0; i < 2; ++i) {
        float tm = -1e30f;
#pragma unroll
        for (int j = 0; j < 4; ++j)
#pragma unroll
            for (int r = 0; r < 4; ++r) tm = fmaxf(tm, sacc[i][j][r]);
        tm = fmaxf(tm, __shfl_xor(tm, 16));
        tm = fmaxf(tm, __shfl_xor(tm, 32));
        float m2 = fmaxf(mrun[i], tm);
        float al = __expf(mrun[i] - m2);
        mrun[i] = m2;
#pragma unroll
        for (int jd = 0; jd < 4; ++jd)
#pragma unroll
            for (int r = 0; r < 4; ++r) cacc[i][jd][r] *= al;
        float ps = 0.f;
#pragma unroll
        for (int j = 0; j < 4; ++j)
#pragma unroll
            for (int r = 0; r < 4; ++r) {
                float p = __expf(sacc[i][j][r] - m2);
                sacc[i][j][r] = p;
                ps += p;
            }
        ps += __shfl_xor(ps, 16);
        ps += __shfl_xor(ps, 32);
        lrun[i] = lrun[i] * al + ps;
    }
    // P -> LDS: row q=i*16+lr, kc=j*16+lg*4+{0..3} consecutive -> 8B writes
#pragma unroll
    for (int i = 0; i < 2; ++i) {
        int q = i * 16 + lr;
#pragma unroll
        for (int j = 0; j < 4; ++j) {
            int kc0 = j * 16 + lg * 4;
            int ks = kc0 >> 3;
            f16x4 pv4;
#pragma unroll
            for (int r = 0; r < 4; ++r) pv4[r] = (_Float16)sacc[i][j][r];
            *(f16x4*)((char*)Ps + q * 128 + ((ks ^ (q & 7)) << 4) + (kc0 & 7) * 2) = pv4;
        }
    }
    // PV: cacc[i][jd] += mfma(V-frag as A, P as B). V direct from global:
    // bv[jd][e] = V[k0+kk*32+lg*8+e][cv + jd*16 + lr]  (A row = d-in-block)
    const _Float16* vb = QKV + (base + k0) * LDQ + cv;
#pragma unroll
    for (int kk = 0; kk < 2; ++kk) {
        f16x8 pa[2], bv[4];
#pragma unroll
        for (int i = 0; i < 2; ++i) pa[i] = ldsfrag(Ps, i * 16 + lr, kk * 4 + lg);
        const _Float16* vk = vb + (size_t)(kk * 32 + lg * 8) * LDQ + lr;
#pragma unroll
        for (int jd = 0; jd < 4; ++jd)
#pragma unroll
            for (int e = 0; e < 8; ++e)
                bv[jd][e] = vk[(size_t)e * LDQ + jd * 16];
        __builtin_amdgcn_s_setprio(1);
#pragma unroll
        for (int i = 0; i < 2; ++i)
#pragma unroll
            for (int jd = 0; jd < 4; ++jd)
                cacc[i][jd] = __builtin_amdgcn_mfma_f32_16x16x32_f16(bv[jd], pa[i], cacc[i][jd], 0, 0, 0);
        __builtin_amdgcn_s_setprio(0);
    }
}

__global__ __launch_bounds__(64) void k_attn(const _Float16* __restrict__ QKV,
                                             _Float16* __restrict__ Og) {
    __shared__ _Float16 Ps[32 * 64];  // P[q][k], swizzled (4 KB)
    int lane = threadIdx.x;
    int id = blockIdx.x;
    int bh = id & 63;
    int qt = (SEQ / 32 - 1) - (id >> 6);  // heavy blocks dispatch first
    int h = bh & 15, b = bh >> 4;
    int q0 = qt * 32;
    int lr = lane & 15, lg = lane >> 4;
    size_t base = (size_t)b * SEQ;
    int cq = h * HDIM, ck = 1024 + h * HDIM, cv = 2048 + h * HDIM;

    // Q fragments (B-operand: col=lane&15 -> q-row, k=(lane>>4)*8+e), scaled
    f16x8 aq[2][2];
#pragma unroll
    for (int i = 0; i < 2; ++i)
#pragma unroll
        for (int kk = 0; kk < 2; ++kk) {
            f16x8 v = *(const f16x8*)(QKV + (base + q0 + i * 16 + lr) * LDQ + cq + kk * 32 + lg * 8);
#pragma unroll
            for (int e = 0; e < 8; ++e) v[e] = v[e] * (_Float16)0.125f;
            aq[i][kk] = v;
        }

    // cacc[i][jd]: D col=lane&15 = q-row (i*16+lr), row = d = jd*16+lg*4+r
    f32x4 cacc[2][4];
#pragma unroll
    for (int i = 0; i < 2; ++i)
#pragma unroll
        for (int j = 0; j < 4; ++j) cacc[i][j] = (f32x4){0.f, 0.f, 0.f, 0.f};
    float mrun[2], lrun[2];
#pragma unroll
    for (int i = 0; i < 2; ++i) { mrun[i] = -1e30f; lrun[i] = 0.f; }

    int ntiles = q0 / 64 + 1;   // 64-wide K/V tiles needed for causal rows
    f16x8 kA[2][4], kB[2][4];
    load_k(QKV, base, 0, ck, lr, lg, kA);
    for (int kt = 0; kt < ntiles; kt += 2) {
        attn_tile_sw(QKV, kA, kB, kt + 1 < ntiles, (kt + 1) * 64,
                     aq, cacc, mrun, lrun, Ps, base, ck, cv,
                     kt * 64, q0, kt == ntiles - 1, lr, lg);
        if (kt + 1 >= ntiles) break;
        attn_tile_sw(QKV, kB, kA, kt + 2 < ntiles, (kt + 2) * 64,
                     aq, cacc, mrun, lrun, Ps, base, ck, cv,
                     (kt + 1) * 64, q0, kt + 1 == ntiles - 1, lr, lg);
    }
    // normalize + write ctx: q = q0+i*16+lr, d = jd*16+lg*4+{0..3} -> 8B stores
#pragma unroll
    for (int i = 0; i < 2; ++i) {
        float rl = 1.0f / lrun[i];
        int qq = q0 + i * 16 + lr;
#pragma unroll
        for (int jd = 0; jd < 4; ++jd) {
            f16x4 o4;
#pragma unroll
            for (int r = 0; r < 4; ++r) o4[r] = (_Float16)(cacc[i][jd][r] * rl);
            *(f16x4*)(Og + (base + qq) * DIM + h * HDIM + jd * 16 + lg * 4) = o4;
        }
    }
}

// ---------------------------------------------------------------------------
extern "C" void kernel_launch(void* const* d_in, const int* in_sizes, int n_in,
                              void* d_out, int out_size, void* d_ws, size_t ws_size,
                              hipStream_t stream) {
    const float* x    = (const float*)d_in[0];
    const float* WQ   = (const float*)d_in[1];
    const float* WK   = (const float*)d_in[2];
    const float* WV   = (const float*)d_in[3];
    const float* Wo   = (const float*)d_in[4];
    const float* bo   = (const float*)d_in[5];
    const float* W1   = (const float*)d_in[6];
    const float* b1   = (const float*)d_in[7];
    const float* W2   = (const float*)d_in[8];
    const float* b2   = (const float*)d_in[9];
    const float* ln1s = (const float*)d_in[10];
    const float* ln1b = (const float*)d_in[11];
    const float* ln2s = (const float*)d_in[12];
    const float* ln2b = (const float*)d_in[13];
    float* out = (float*)d_out;
    char* ws = (char*)d_ws;
    const size_t MB = 1024 * 1024;
    _Float16* WTqkv = (_Float16*)(ws + 0 * MB);   // [3072][1024] = 6MB
    _Float16* WTo   = (_Float16*)(ws + 6 * MB);   // contiguous after WTqkv
    _Float16* WT1   = (_Float16*)(ws + 8 * MB);   // [4096][1024]
    _Float16* WT2   = (_Float16*)(ws + 16 * MB);  // [1024][4096]
    _Float16* h1    = (_Float16*)(ws + 24 * MB);
    _Float16* qkvb  = (_Float16*)(ws + 32 * MB);  // [4096][3072] = 24MB
    _Float16* ctx   = (_Float16*)(ws + 56 * MB);
    _Float16* h2    = (_Float16*)(ws + 64 * MB);
    _Float16* ff1   = (_Float16*)(ws + 72 * MB);  // [4096][4096] = 32MB
    float*    x2    = (float*)   (ws + 104 * MB); // fp32 residual = 16MB

    dim3 tb(32, 8);
    k_tcvt4<<<dim3(32, 32, 4), tb, 0, stream>>>(WQ, WK, WV, Wo, WTqkv);
    k_tcvt<<<dim3(128, 32), tb, 0, stream>>>(W1, WT1, 1024, 4096);
    k_tcvt<<<dim3(32, 128), tb, 0, stream>>>(W2, WT2, 4096, 1024);

    k_ln<<<MTOT, 256, 0, stream>>>(x, ln1s, ln1b, h1);

    // fused QKV: [4096,1024] x [1024,3072] -> [4096,3072]  (24x32 tiles)
    k_gemm<0><<<dim3(768), 256, 0, stream>>>(h1, WTqkv, LDQ, DIM, 24, qkvb, nullptr);

    k_attn<<<dim3(2048), 64, 0, stream>>>(qkvb, ctx);

    // x2 = x + ctx @ Wo + bo   (512 blocks of 128x64, 3-deep pipeline)
    k_gemm64<<<dim3(512), 256, 0, stream>>>(ctx, WTo, DIM, DIM, x2, bo, x);

    k_ln<<<MTOT, 256, 0, stream>>>(x2, ln2s, ln2b, h2);

    // ff1 = gelu(h2 @ W1 + b1)  (32x32 tiles)
    k_gemm<1><<<dim3(1024), 256, 0, stream>>>(h2, WT1, DFF, DIM, 32, ff1, b1);

    // out = x2 + ff1 @ W2 + b2  (512 blocks of 128x64, 3-deep pipeline)
    k_gemm64<<<dim3(512), 256, 0, stream>>>(ff1, WT2, DIM, DFF, out, b2, x2);
}